// Round 1
// baseline (8734.417 us; speedup 1.0000x reference)
//
#include <hip/hip_runtime.h>
#include <hip/hip_fp16.h>

#define T_STEPS 512
#define BATCH   64
#define HID     512

// ---------------------------------------------------------------------------
// Kernel 1: convert w_hh (fp32, [512][512]) to f16 in workspace.
// ---------------------------------------------------------------------------
__global__ __launch_bounds__(256) void wcvt_kernel(const float* __restrict__ w,
                                                   __half* __restrict__ o) {
    const int i = (blockIdx.x * 256 + threadIdx.x) * 4;   // 256 blocks * 256 thr * 4
    float4 v = *(const float4*)(w + i);
    __half2 p0; p0.x = __float2half(v.x); p0.y = __float2half(v.y);
    __half2 p1; p1.x = __float2half(v.z); p1.y = __float2half(v.w);
    *(__half2*)(o + i)     = p0;
    *(__half2*)(o + i + 2) = p1;
}

// ---------------------------------------------------------------------------
// Kernel 2: xproj GEMM. out[m][n] = sum_k x[m][k] * w_ih[n][k] + b_ih[n]+b_hh[n]
// m = t*64+b (32768 rows), n = hidden (512). Both operands K-contiguous.
// 64x64 tile, 256 threads, 4x4 outputs/thread, K-chunks of 16.
// LDS layout k-outer so fragment reads are ds_read_b128.
// ---------------------------------------------------------------------------
__global__ __launch_bounds__(256) void xproj_gemm(
    const float* __restrict__ x, const float* __restrict__ w_ih,
    const float* __restrict__ b_ih, const float* __restrict__ b_hh,
    float* __restrict__ out)
{
    __shared__ __align__(16) float As[16][68];   // [k][m], pad 68 keeps 16B align
    __shared__ __align__(16) float Bs[16][68];   // [k][n]

    const int tid   = threadIdx.x;
    const int tx    = tid & 15;          // n-quad
    const int ty    = tid >> 4;          // m-quad
    const int mBase = blockIdx.y * 64;
    const int nBase = blockIdx.x * 64;
    const int ldr   = tid >> 2;          // 0..63 (row within tile)
    const int ldk   = (tid & 3) * 4;     // 0,4,8,12 (k offset)

    float acc[4][4] = {};

    const float* aptr = x    + (size_t)(mBase + ldr) * 512 + ldk;
    const float* bptr = w_ih + (size_t)(nBase + ldr) * 512 + ldk;

    for (int k0 = 0; k0 < 512; k0 += 16) {
        float4 av = *(const float4*)(aptr + k0);
        float4 bv = *(const float4*)(bptr + k0);
        __syncthreads();                 // previous chunk's reads complete
        As[ldk + 0][ldr] = av.x; As[ldk + 1][ldr] = av.y;
        As[ldk + 2][ldr] = av.z; As[ldk + 3][ldr] = av.w;
        Bs[ldk + 0][ldr] = bv.x; Bs[ldk + 1][ldr] = bv.y;
        Bs[ldk + 2][ldr] = bv.z; Bs[ldk + 3][ldr] = bv.w;
        __syncthreads();
#pragma unroll
        for (int kk = 0; kk < 16; ++kk) {
            float4 a = *(const float4*)&As[kk][ty * 4];
            float4 b = *(const float4*)&Bs[kk][tx * 4];
            float ar[4] = {a.x, a.y, a.z, a.w};
            float br[4] = {b.x, b.y, b.z, b.w};
#pragma unroll
            for (int i = 0; i < 4; ++i)
#pragma unroll
                for (int j = 0; j < 4; ++j)
                    acc[i][j] = fmaf(ar[i], br[j], acc[i][j]);
        }
    }

    // epilogue: bias add, float4 coalesced store
    const int n0 = nBase + tx * 4;
    float bias[4];
#pragma unroll
    for (int j = 0; j < 4; ++j) bias[j] = b_ih[n0 + j] + b_hh[n0 + j];
#pragma unroll
    for (int i = 0; i < 4; ++i) {
        const int m = mBase + ty * 4 + i;
        float4 v = {acc[i][0] + bias[0], acc[i][1] + bias[1],
                    acc[i][2] + bias[2], acc[i][3] + bias[3]};
        *(float4*)(out + (size_t)m * 512 + n0) = v;
    }
}

// ---------------------------------------------------------------------------
// Kernel 3: recurrent scan. One workgroup per batch element; 512 threads,
// thread j owns output row j (reads W_hh row j). h double-buffered in LDS
// as f16; one __syncthreads per step. Reads xp from d_out, overwrites with h.
// ---------------------------------------------------------------------------
typedef _Float16 half2v __attribute__((ext_vector_type(2)));
union F4H { float4 f; half2v h[4]; __half2 hh[4]; };

__device__ inline float dot2f(half2v a, half2v b, float c) {
#if __has_builtin(__builtin_amdgcn_fdot2)
    return __builtin_amdgcn_fdot2(a, b, c, false);
#else
    return fmaf((float)a[0], (float)b[0], fmaf((float)a[1], (float)b[1], c));
#endif
}

template <int USE_F16>
__global__ __launch_bounds__(512) void rnn_scan(const void* __restrict__ wv,
                                                float* __restrict__ out)
{
    __shared__ __align__(16) __half hs[2][HID];
    const int b = blockIdx.x;
    const int j = threadIdx.x;

    hs[0][j] = __float2half(0.f);
    __syncthreads();

    const __half* wrow16 = (const __half*)wv + (size_t)j * HID;
    const float*  wrow32 = (const float*)wv + (size_t)j * HID;

    float* outb = out + (size_t)b * HID + j;
    int cur = 0;
    float hn = 0.f;

    for (int t = 0; t < T_STEPS; ++t) {
        float a0 = outb[(size_t)t * (BATCH * HID)];  // xp (written by xproj_gemm)
        float a1 = 0.f, a2 = 0.f, a3 = 0.f;          // 4-way ILP accumulators

        if (USE_F16) {
#pragma unroll 8
            for (int k0 = 0; k0 < HID; k0 += 8) {
                F4H w; w.f = *(const float4*)(wrow16 + k0);
                F4H h; h.f = *(const float4*)(&hs[cur][k0]);
                a0 = dot2f(w.h[0], h.h[0], a0);
                a1 = dot2f(w.h[1], h.h[1], a1);
                a2 = dot2f(w.h[2], h.h[2], a2);
                a3 = dot2f(w.h[3], h.h[3], a3);
            }
        } else {
#pragma unroll 4
            for (int k0 = 0; k0 < HID; k0 += 8) {
                float4 w0 = *(const float4*)(wrow32 + k0);
                float4 w1 = *(const float4*)(wrow32 + k0 + 4);
                F4H h; h.f = *(const float4*)(&hs[cur][k0]);
                float2 h0 = __half22float2(h.hh[0]);
                float2 h1 = __half22float2(h.hh[1]);
                float2 h2 = __half22float2(h.hh[2]);
                float2 h3 = __half22float2(h.hh[3]);
                a0 = fmaf(w0.x, h0.x, a0); a1 = fmaf(w0.y, h0.y, a1);
                a2 = fmaf(w0.z, h1.x, a2); a3 = fmaf(w0.w, h1.y, a3);
                a0 = fmaf(w1.x, h2.x, a0); a1 = fmaf(w1.y, h2.y, a1);
                a2 = fmaf(w1.z, h3.x, a2); a3 = fmaf(w1.w, h3.y, a3);
            }
        }
        hn = tanhf((a0 + a1) + (a2 + a3));
        outb[(size_t)t * (BATCH * HID)] = hn;        // in-place: xp -> h_t
        hs[cur ^ 1][j] = __float2half(hn);           // other buffer: no race
        __syncthreads();
        cur ^= 1;
    }
    // h_n tail: [1, B, H] right after output[T,B,H]
    out[(size_t)T_STEPS * BATCH * HID + (size_t)b * HID + j] = hn;
}

// ---------------------------------------------------------------------------
extern "C" void kernel_launch(void* const* d_in, const int* in_sizes, int n_in,
                              void* d_out, int out_size, void* d_ws, size_t ws_size,
                              hipStream_t stream) {
    const float* x    = (const float*)d_in[0];
    const float* w_ih = (const float*)d_in[1];
    const float* w_hh = (const float*)d_in[2];
    const float* b_ih = (const float*)d_in[3];
    const float* b_hh = (const float*)d_in[4];
    float* out = (float*)d_out;

    const bool f16 = ws_size >= (size_t)HID * HID * sizeof(__half);
    if (f16) {
        wcvt_kernel<<<256, 256, 0, stream>>>(w_hh, (__half*)d_ws);
    }
    xproj_gemm<<<dim3(8, 512), 256, 0, stream>>>(x, w_ih, b_ih, b_hh, out);
    if (f16) {
        rnn_scan<1><<<BATCH, HID, 0, stream>>>(d_ws, out);
    } else {
        rnn_scan<0><<<BATCH, HID, 0, stream>>>(w_hh, out);
    }
}

// Round 2
// 1175.526 us; speedup vs baseline: 7.4302x; 7.4302x over previous
//
#include <hip/hip_runtime.h>
#include <hip/hip_fp16.h>

#define T_STEPS 512
#define BATCH   64
#define HID     512

// Row split (chunks of 8 f16 = one float4):
#define CH_REG  36                  // register-resident chunks   (144 VGPRs)
#define CH_LDS  7                   // LDS-resident chunks        (56 KB)
#define CH_STRA 11                  // streamed batch A
#define CH_STRB 10                  // streamed batch B  (36+7+11+10 = 64)

// ---------------------------------------------------------------------------
// Kernel 1: convert w_hh (fp32, [512][512]) to f16 in workspace.
// ---------------------------------------------------------------------------
__global__ __launch_bounds__(256) void wcvt_kernel(const float* __restrict__ w,
                                                   __half* __restrict__ o) {
    const int i = (blockIdx.x * 256 + threadIdx.x) * 4;
    float4 v = *(const float4*)(w + i);
    __half2 p0; p0.x = __float2half(v.x); p0.y = __float2half(v.y);
    __half2 p1; p1.x = __float2half(v.z); p1.y = __float2half(v.w);
    *(__half2*)(o + i)     = p0;
    *(__half2*)(o + i + 2) = p1;
}

// ---------------------------------------------------------------------------
// Kernel 2: xproj GEMM (unchanged from R1 — ~200 us, not the bottleneck yet).
// out[m][n] = sum_k x[m][k]*w_ih[n][k] + b_ih[n] + b_hh[n]
// ---------------------------------------------------------------------------
__global__ __launch_bounds__(256) void xproj_gemm(
    const float* __restrict__ x, const float* __restrict__ w_ih,
    const float* __restrict__ b_ih, const float* __restrict__ b_hh,
    float* __restrict__ out)
{
    __shared__ __align__(16) float As[16][68];
    __shared__ __align__(16) float Bs[16][68];

    const int tid   = threadIdx.x;
    const int tx    = tid & 15;
    const int ty    = tid >> 4;
    const int mBase = blockIdx.y * 64;
    const int nBase = blockIdx.x * 64;
    const int ldr   = tid >> 2;
    const int ldk   = (tid & 3) * 4;

    float acc[4][4] = {};

    const float* aptr = x    + (size_t)(mBase + ldr) * 512 + ldk;
    const float* bptr = w_ih + (size_t)(nBase + ldr) * 512 + ldk;

    for (int k0 = 0; k0 < 512; k0 += 16) {
        float4 av = *(const float4*)(aptr + k0);
        float4 bv = *(const float4*)(bptr + k0);
        __syncthreads();
        As[ldk + 0][ldr] = av.x; As[ldk + 1][ldr] = av.y;
        As[ldk + 2][ldr] = av.z; As[ldk + 3][ldr] = av.w;
        Bs[ldk + 0][ldr] = bv.x; Bs[ldk + 1][ldr] = bv.y;
        Bs[ldk + 2][ldr] = bv.z; Bs[ldk + 3][ldr] = bv.w;
        __syncthreads();
#pragma unroll
        for (int kk = 0; kk < 16; ++kk) {
            float4 a = *(const float4*)&As[kk][ty * 4];
            float4 b = *(const float4*)&Bs[kk][tx * 4];
            float ar[4] = {a.x, a.y, a.z, a.w};
            float br[4] = {b.x, b.y, b.z, b.w};
#pragma unroll
            for (int i = 0; i < 4; ++i)
#pragma unroll
                for (int j = 0; j < 4; ++j)
                    acc[i][j] = fmaf(ar[i], br[j], acc[i][j]);
        }
    }

    const int n0 = nBase + tx * 4;
    float bias[4];
#pragma unroll
    for (int j = 0; j < 4; ++j) bias[j] = b_ih[n0 + j] + b_hh[n0 + j];
#pragma unroll
    for (int i = 0; i < 4; ++i) {
        const int m = mBase + ty * 4 + i;
        float4 v = {acc[i][0] + bias[0], acc[i][1] + bias[1],
                    acc[i][2] + bias[2], acc[i][3] + bias[3]};
        *(float4*)(out + (size_t)m * 512 + n0) = v;
    }
}

// ---------------------------------------------------------------------------
// Kernel 3: recurrent scan v2 — W split register/LDS/stream, xp prefetch.
// One WG per batch element, 512 threads, thread j owns output row j.
// ---------------------------------------------------------------------------
typedef _Float16 half2v __attribute__((ext_vector_type(2)));
union F4H { float4 f; half2v h[4]; __half2 hh[4]; };

__device__ inline float dot2f(half2v a, half2v b, float c) {
#if __has_builtin(__builtin_amdgcn_fdot2)
    return __builtin_amdgcn_fdot2(a, b, c, false);
#else
    return fmaf((float)a[0], (float)b[0], fmaf((float)a[1], (float)b[1], c));
#endif
}

#define ACC4(WF, G) do {                                        \
    F4H hh_; hh_.f = *(const float4*)(hrow + (G) * 8);          \
    F4H ww_; ww_.f = (WF);                                      \
    a0 = dot2f(ww_.h[0], hh_.h[0], a0);                         \
    a1 = dot2f(ww_.h[1], hh_.h[1], a1);                         \
    a2 = dot2f(ww_.h[2], hh_.h[2], a2);                         \
    a3 = dot2f(ww_.h[3], hh_.h[3], a3); } while (0)

__global__ __launch_bounds__(512, 2) void rnn_scan2(
    const __half* __restrict__ w16, float* __restrict__ out)
{
    __shared__ __align__(16) float4 wlds[HID][CH_LDS];   // 56 KB
    __shared__ __align__(16) __half hbuf[2][HID];        // 2 KB

    const int b = blockIdx.x;
    const int j = threadIdx.x;

    const __half* wrow = w16 + (size_t)j * HID;

    // Preload register-resident W chunks (0..35)
    float4 wreg[CH_REG];
#pragma unroll
    for (int c = 0; c < CH_REG; ++c)
        wreg[c] = *(const float4*)(wrow + c * 8);

    // Stage LDS-resident W chunks (36..42)
#pragma unroll
    for (int c = 0; c < CH_LDS; ++c)
        wlds[j][c] = *(const float4*)(wrow + (CH_REG + c) * 8);

    hbuf[0][j] = __float2half(0.f);
    __syncthreads();

    float* outb = out + (size_t)b * HID + j;
    const size_t stride = (size_t)BATCH * HID;
    const __half* wstr = wrow + (CH_REG + CH_LDS) * 8;   // streamed chunks 43..63

    int cur = 0;
    float hn = 0.f;
    float xp_next = outb[0];

    for (int t = 0; t < T_STEPS; ++t) {
        const float xp = xp_next;
        const int tn = (t + 1 < T_STEPS) ? (t + 1) : t;
        xp_next = outb[(size_t)tn * stride];             // prefetch next xp

        const __half* hrow = hbuf[cur];

        // Issue streamed batch A (chunks 43..53)
        float4 wa[CH_STRA];
#pragma unroll
        for (int c = 0; c < CH_STRA; ++c)
            wa[c] = *(const float4*)(wstr + c * 8);

        float a0 = xp, a1 = 0.f, a2 = 0.f, a3 = 0.f;

        // Register part 1 (chunks 0..17) — hides batch-A latency
#pragma unroll
        for (int c = 0; c < 18; ++c) ACC4(wreg[c], c);

        // Consume batch A
#pragma unroll
        for (int c = 0; c < CH_STRA; ++c) ACC4(wa[c], CH_REG + CH_LDS + c);

        // Issue streamed batch B (chunks 54..63)
        float4 wb[CH_STRB];
#pragma unroll
        for (int c = 0; c < CH_STRB; ++c)
            wb[c] = *(const float4*)(wstr + (CH_STRA + c) * 8);

        // Register part 2 (chunks 18..35) + LDS part (36..42) — hides batch-B
#pragma unroll
        for (int c = 18; c < CH_REG; ++c) ACC4(wreg[c], c);
#pragma unroll
        for (int c = 0; c < CH_LDS; ++c) ACC4(wlds[j][c], CH_REG + c);

        // Consume batch B
#pragma unroll
        for (int c = 0; c < CH_STRB; ++c)
            ACC4(wb[c], CH_REG + CH_LDS + CH_STRA + c);

        hn = tanhf((a0 + a1) + (a2 + a3));
        outb[(size_t)t * stride] = hn;                   // in-place xp -> h_t
        hbuf[cur ^ 1][j] = __float2half(hn);
        __syncthreads();
        cur ^= 1;
    }
    out[(size_t)T_STEPS * stride + (size_t)b * HID + j] = hn;
}

// ---------------------------------------------------------------------------
// Fallback scan (fp32 streaming) if workspace can't hold f16 W — correctness
// safety net only.
// ---------------------------------------------------------------------------
__global__ __launch_bounds__(512) void rnn_scan_f32(const float* __restrict__ w,
                                                    float* __restrict__ out)
{
    __shared__ __align__(16) __half hs[2][HID];
    const int b = blockIdx.x;
    const int j = threadIdx.x;

    hs[0][j] = __float2half(0.f);
    __syncthreads();

    const float* wrow32 = w + (size_t)j * HID;
    float* outb = out + (size_t)b * HID + j;
    int cur = 0;
    float hn = 0.f;

    for (int t = 0; t < T_STEPS; ++t) {
        float a0 = outb[(size_t)t * (BATCH * HID)];
        float a1 = 0.f, a2 = 0.f, a3 = 0.f;
#pragma unroll 4
        for (int k0 = 0; k0 < HID; k0 += 8) {
            float4 w0 = *(const float4*)(wrow32 + k0);
            float4 w1 = *(const float4*)(wrow32 + k0 + 4);
            F4H h; h.f = *(const float4*)(&hs[cur][k0]);
            float2 h0 = __half22float2(h.hh[0]);
            float2 h1 = __half22float2(h.hh[1]);
            float2 h2 = __half22float2(h.hh[2]);
            float2 h3 = __half22float2(h.hh[3]);
            a0 = fmaf(w0.x, h0.x, a0); a1 = fmaf(w0.y, h0.y, a1);
            a2 = fmaf(w0.z, h1.x, a2); a3 = fmaf(w0.w, h1.y, a3);
            a0 = fmaf(w1.x, h2.x, a0); a1 = fmaf(w1.y, h2.y, a1);
            a2 = fmaf(w1.z, h3.x, a2); a3 = fmaf(w1.w, h3.y, a3);
        }
        hn = tanhf((a0 + a1) + (a2 + a3));
        outb[(size_t)t * (BATCH * HID)] = hn;
        hs[cur ^ 1][j] = __float2half(hn);
        __syncthreads();
        cur ^= 1;
    }
    out[(size_t)T_STEPS * BATCH * HID + (size_t)b * HID + j] = hn;
}

// ---------------------------------------------------------------------------
extern "C" void kernel_launch(void* const* d_in, const int* in_sizes, int n_in,
                              void* d_out, int out_size, void* d_ws, size_t ws_size,
                              hipStream_t stream) {
    const float* x    = (const float*)d_in[0];
    const float* w_ih = (const float*)d_in[1];
    const float* w_hh = (const float*)d_in[2];
    const float* b_ih = (const float*)d_in[3];
    const float* b_hh = (const float*)d_in[4];
    float* out = (float*)d_out;

    const bool f16 = ws_size >= (size_t)HID * HID * sizeof(__half);
    if (f16) {
        wcvt_kernel<<<256, 256, 0, stream>>>(w_hh, (__half*)d_ws);
    }
    xproj_gemm<<<dim3(8, 512), 256, 0, stream>>>(x, w_ih, b_ih, b_hh, out);
    if (f16) {
        rnn_scan2<<<BATCH, HID, 0, stream>>>((const __half*)d_ws, out);
    } else {
        rnn_scan_f32<<<BATCH, HID, 0, stream>>>(w_hh, out);
    }
}